// Round 9
// baseline (226.083 us; speedup 1.0000x reference)
//
#include <hip/hip_runtime.h>
#include <hip/hip_bf16.h>

#define N_NODES 140000
#define N_EDGES 2240000
#define NFEAT 128
#define NHID 128
#define N_FRAMES 14
#define NODES_PER_FRAME 10000
#define CAP 352            // int2 LDS slots per wave (7 frames padded to x8)
#define GEMM_BLOCKS ((N_NODES + 63) / 64)
#define PREP_BLOCKS ((N_EDGES + 255) / 256)

typedef __attribute__((ext_vector_type(8))) short frag_b16;
typedef __attribute__((ext_vector_type(4))) int frag_i4;
typedef __attribute__((ext_vector_type(4))) float f32x4;

__device__ __forceinline__ unsigned short f2bf(float f) {
    union { float f; unsigned int u; } v; v.f = f;
    unsigned int r = v.u + 0x7fffu + ((v.u >> 16) & 1u);   // RNE
    return (unsigned short)(r >> 16);
}
__device__ __forceinline__ int pk_bf16(float a, float b) {
    union { __hip_bfloat162 h; int i; } u;
    u.h = __float22bfloat162_rn(make_float2(a, b));        // v_cvt_pk_bf16_f32
    return u.i;
}

// ---------------------------------------------------------------------------
// Fused GEMM + prep. blockIdx < GEMM_BLOCKS: support = x@W with int8-row-quant
// epilogue (W transposed+converted fp32->bf16 directly into LDS — no global
// WT intermediate, no inter-kernel ordering hazard). Remaining blocks: CSR
// row_ptr build from sorted COO rows. The streaming prep blocks co-schedule
// with the MFMA blocks (separate pipes), hiding prep entirely.
// ---------------------------------------------------------------------------
#define WT_STRIDE 136

__global__ __launch_bounds__(256) void gemm_prep_kernel(
        const float* __restrict__ x, const float* __restrict__ W,
        unsigned char* __restrict__ supQ, float* __restrict__ scales,
        const int* __restrict__ edge_row, int* __restrict__ row_ptr) {
    __shared__ unsigned short wt_lds[128 * WT_STRIDE];

    if (blockIdx.x >= GEMM_BLOCKS) {
        // ---- prep block: CSR offsets ----
        int e = (blockIdx.x - GEMM_BLOCKS) * 256 + threadIdx.x;
        if (e < N_EDGES) {
            int r = edge_row[e];
            int prev = (e == 0) ? -1 : edge_row[e - 1];
            for (int q = prev + 1; q <= r; ++q) row_ptr[q] = e;
            if (e == N_EDGES - 1) {
                for (int q = r + 1; q <= N_NODES; ++q) row_ptr[q] = N_EDGES;
            }
        }
        return;
    }

    // ---- gemm block ----
    // stage W (fp32 k-major) transposed+converted into wt_lds[n][k]
    const float4* Wv = (const float4*)W;               // 4096 float4
    for (int idx = threadIdx.x; idx < 4096; idx += 256) {
        float4 d = Wv[idx];
        int k = idx >> 5;                              // 32 float4 per k-row
        int n0 = (idx & 31) << 2;
        wt_lds[(n0 + 0) * WT_STRIDE + k] = f2bf(d.x);
        wt_lds[(n0 + 1) * WT_STRIDE + k] = f2bf(d.y);
        wt_lds[(n0 + 2) * WT_STRIDE + k] = f2bf(d.z);
        wt_lds[(n0 + 3) * WT_STRIDE + k] = f2bf(d.w);
    }

    int wave = threadIdx.x >> 6;
    int lane = threadIdx.x & 63;
    int m = lane & 15;
    int q = lane >> 4;

    long row0 = (long)blockIdx.x * 64 + wave * 16;

    int arow = (int)row0 + m;
    if (arow >= N_NODES) arow = N_NODES - 1;
    const float* xrow = x + (long)arow * 128 + q * 8;
    frag_b16 xa[4];
#pragma unroll
    for (int ks = 0; ks < 4; ++ks) {
        float4 lo = *(const float4*)(xrow + ks * 32);
        float4 hi = *(const float4*)(xrow + ks * 32 + 4);
        union { frag_b16 f; frag_i4 i; } u;
        u.i[0] = pk_bf16(lo.x, lo.y);
        u.i[1] = pk_bf16(lo.z, lo.w);
        u.i[2] = pk_bf16(hi.x, hi.y);
        u.i[3] = pk_bf16(hi.z, hi.w);
        xa[ks] = u.f;
    }

    __syncthreads();

    if (row0 < N_NODES) {
        f32x4 acc[8];
#pragma unroll
        for (int t = 0; t < 8; ++t) acc[t] = (f32x4){0.f, 0.f, 0.f, 0.f};

#pragma unroll
        for (int t = 0; t < 8; ++t) {
            const unsigned short* bp = &wt_lds[(t * 16 + m) * WT_STRIDE + q * 8];
#pragma unroll
            for (int ks = 0; ks < 4; ++ks) {
                frag_b16 wfrag = *(const frag_b16*)(bp + ks * 32);
                acc[t] = __builtin_amdgcn_mfma_f32_16x16x32_bf16(wfrag, xa[ks], acc[t], 0, 0, 0);
            }
        }

        // --- int8 row quantization epilogue ---
        float amax = 0.f;
#pragma unroll
        for (int t = 0; t < 8; ++t)
#pragma unroll
            for (int r = 0; r < 4; ++r) amax = fmaxf(amax, fabsf(acc[t][r]));
        amax = fmaxf(amax, __shfl_xor(amax, 16));
        amax = fmaxf(amax, __shfl_xor(amax, 32));
        float rinv = amax > 0.f ? 127.f / amax : 0.f;

        long node = row0 + m;
        if (node < N_NODES) {
            if (q == 0) scales[node] = amax * (1.f / 127.f);
            unsigned char* srow = supQ + node * 128;
#pragma unroll
            for (int t = 0; t < 8; ++t) {
                unsigned u0 = (unsigned)(rintf(acc[t][0] * rinv) + 128.f);
                unsigned u1 = (unsigned)(rintf(acc[t][1] * rinv) + 128.f);
                unsigned u2 = (unsigned)(rintf(acc[t][2] * rinv) + 128.f);
                unsigned u3 = (unsigned)(rintf(acc[t][3] * rinv) + 128.f);
                *(unsigned*)(srow + t * 16 + q * 4) = u0 | (u1 << 8) | (u2 << 16) | (u3 << 24);
            }
        }
    }
}

// ---------------------------------------------------------------------------
// Fused aggregation v6 (= R7's proven inner loop + in-staging scale fold).
// Block = 128 thr = 2 waves = 1 output node. Wave w: frames [7w, 7w+6].
// Lane = (eh = lane>>4: edge-of-quad, f8 = lane&15: feature octet) -> one
// dwordx2 gather = 8 features, 4 edges per wave-instruction, one 128B line
// per edge row. eBuf stores {col<<7, valp = edge_val*scales[col]}; staging is
// STRAIGHT-LINE over the 7 frames (21 independent loads in flight; fit
// requires maxlen<=64) and also wave-reduces svf_f = sum(valp) per frame so
// the inner loop carries no svf adds. -128 bias applied once per frame via
// svf. Segments padded-to-8 with {0,0} (exact fma identity, row-0 pads hot).
// ---------------------------------------------------------------------------
__global__ __launch_bounds__(128) void agg_kernel(
        const unsigned char* __restrict__ supQ, const float* __restrict__ scales,
        const float* __restrict__ b,
        const float* __restrict__ edge_val, const int* __restrict__ edge_col,
        const int* __restrict__ row_ptr, float* __restrict__ out) {
    __shared__ int    segStart[2][8];
    __shared__ int    segLen[2][8];
    __shared__ int    segOff[2][8];
    __shared__ float  segSvf[2][7];
    __shared__ int2   eBuf[2][CAP];
    __shared__ float4 xch[2][16][2];

    const int i = blockIdx.x;
    const int lane = threadIdx.x & 63;
    const int w = threadIdx.x >> 6;
    const int eh = lane >> 4;                          // edge-of-quad 0..3
    const int f8 = lane & 15;                          // feature octet
    const unsigned f8x8 = (unsigned)f8 * 8u;

    // --- CSR ranges in lanes 0..6; padded-to-8 exclusive scan ---
    int a = 0, len = 0;
    if (lane < 7) {
        int n = (w * 7 + lane) * NODES_PER_FRAME + i;
        a = row_ptr[n];
        len = row_ptr[n + 1] - a;
    }
    int ml = len;
    ml = max(ml, __shfl_xor(ml, 1));
    ml = max(ml, __shfl_xor(ml, 2));
    ml = max(ml, __shfl_xor(ml, 4));
    const int maxlen = __shfl(ml, 0);                  // wave-uniform

    int len8 = (len + 7) & ~7;
    int off = 0;
#pragma unroll
    for (int f2 = 0; f2 < 7; ++f2) {
        int L2 = __shfl(len8, f2);
        if (f2 < lane) off += L2;
    }
    if (lane < 7) { segStart[w][lane] = a; segLen[w][lane] = len; segOff[w][lane] = off; }
    if (lane == 6) segOff[w][7] = off + len8;
    __syncthreads();

    const bool fit = (segOff[w][7] <= CAP) && (maxlen <= 64);  // wave-uniform

    // --- stage (col<<7, valp) into LDS, straight-line over 7 frames,
    //     wave-reducing svf_f as we go ---
    if (fit) {
#pragma unroll
        for (int f = 0; f < 7; ++f) {
            int aF = __shfl(a, f), lF = __shfl(len, f), sF = __shfl(off, f);
            int L8 = (lF + 7) & ~7;
            int2 v = make_int2(0, 0);
            if (lane < lF) {
                int c = edge_col[aF + lane];
                v.x = c << 7;
                v.y = __float_as_int(edge_val[aF + lane] * scales[c]);
            }
            if (lane < L8) eBuf[w][sF + lane] = v;
            float sv = __int_as_float(v.y);            // 0 for pads/inactive
            sv += __shfl_xor(sv, 1);  sv += __shfl_xor(sv, 2);
            sv += __shfl_xor(sv, 4);  sv += __shfl_xor(sv, 8);
            sv += __shfl_xor(sv, 16); sv += __shfl_xor(sv, 32);
            if (lane == 0) segSvf[w][f] = sv;
        }
    }
    __syncthreads();

    const float4 blo = *(const float4*)&b[f8 * 8];
    const float4 bhi = *(const float4*)&b[f8 * 8 + 4];
    float m0 = 0.f, m1 = 0.f, m2 = 0.f, m3 = 0.f;      // relu => max >= 0
    float m4 = 0.f, m5 = 0.f, m6 = 0.f, m7 = 0.f;

    if (fit) {
#pragma unroll 1
        for (int f = 0; f < 7; ++f) {
            int s = segOff[w][f];
            int e8 = s + ((segLen[w][f] + 7) & ~7);
            float a0 = 0.f, a1 = 0.f, a2 = 0.f, a3 = 0.f;
            float a4 = 0.f, a5 = 0.f, a6 = 0.f, a7 = 0.f;
            for (int j = s; j < e8; j += 8) {
                int2 e0 = eBuf[w][j + eh];
                int2 e1 = eBuf[w][j + 4 + eh];
                uint2 q0 = *(const uint2*)(supQ + ((unsigned)e0.x | f8x8));
                uint2 q1 = *(const uint2*)(supQ + ((unsigned)e1.x | f8x8));
                float v0 = __int_as_float(e0.y);
                float v1 = __int_as_float(e1.y);
                a0 = fmaf(v0, (float)( q0.x        & 0xffu), a0);
                a1 = fmaf(v0, (float)((q0.x >> 8)  & 0xffu), a1);
                a2 = fmaf(v0, (float)((q0.x >> 16) & 0xffu), a2);
                a3 = fmaf(v0, (float)( q0.x >> 24        ), a3);
                a4 = fmaf(v0, (float)( q0.y        & 0xffu), a4);
                a5 = fmaf(v0, (float)((q0.y >> 8)  & 0xffu), a5);
                a6 = fmaf(v0, (float)((q0.y >> 16) & 0xffu), a6);
                a7 = fmaf(v0, (float)( q0.y >> 24        ), a7);
                a0 = fmaf(v1, (float)( q1.x        & 0xffu), a0);
                a1 = fmaf(v1, (float)((q1.x >> 8)  & 0xffu), a1);
                a2 = fmaf(v1, (float)((q1.x >> 16) & 0xffu), a2);
                a3 = fmaf(v1, (float)( q1.x >> 24        ), a3);
                a4 = fmaf(v1, (float)( q1.y        & 0xffu), a4);
                a5 = fmaf(v1, (float)((q1.y >> 8)  & 0xffu), a5);
                a6 = fmaf(v1, (float)((q1.y >> 16) & 0xffu), a6);
                a7 = fmaf(v1, (float)( q1.y >> 24        ), a7);
            }
            // reduce across the 4 edge-quads (xor 16, 32)
            a0 += __shfl_xor(a0, 16); a1 += __shfl_xor(a1, 16);
            a2 += __shfl_xor(a2, 16); a3 += __shfl_xor(a3, 16);
            a4 += __shfl_xor(a4, 16); a5 += __shfl_xor(a5, 16);
            a6 += __shfl_xor(a6, 16); a7 += __shfl_xor(a7, 16);
            a0 += __shfl_xor(a0, 32); a1 += __shfl_xor(a1, 32);
            a2 += __shfl_xor(a2, 32); a3 += __shfl_xor(a3, 32);
            a4 += __shfl_xor(a4, 32); a5 += __shfl_xor(a5, 32);
            a6 += __shfl_xor(a6, 32); a7 += __shfl_xor(a7, 32);
            float svf = segSvf[w][f];
            float h0 = fmaf(-128.f, svf, a0) + blo.x;
            float h1 = fmaf(-128.f, svf, a1) + blo.y;
            float h2 = fmaf(-128.f, svf, a2) + blo.z;
            float h3 = fmaf(-128.f, svf, a3) + blo.w;
            float h4 = fmaf(-128.f, svf, a4) + bhi.x;
            float h5 = fmaf(-128.f, svf, a5) + bhi.y;
            float h6 = fmaf(-128.f, svf, a6) + bhi.z;
            float h7 = fmaf(-128.f, svf, a7) + bhi.w;
            m0 = fmaxf(m0, fmaxf(h0, 0.f)); m1 = fmaxf(m1, fmaxf(h1, 0.f));
            m2 = fmaxf(m2, fmaxf(h2, 0.f)); m3 = fmaxf(m3, fmaxf(h3, 0.f));
            m4 = fmaxf(m4, fmaxf(h4, 0.f)); m5 = fmaxf(m5, fmaxf(h5, 0.f));
            m6 = fmaxf(m6, fmaxf(h6, 0.f)); m7 = fmaxf(m7, fmaxf(h7, 0.f));
        }
    } else {
        // safety fallback: direct global reads, same math, quads split by eh
#pragma unroll 1
        for (int f = 0; f < 7; ++f) {
            int g = segStart[w][f], L = segLen[w][f];
            float a0 = 0.f, a1 = 0.f, a2 = 0.f, a3 = 0.f;
            float a4 = 0.f, a5 = 0.f, a6 = 0.f, a7 = 0.f, svf = 0.f;
            for (int j = eh; j < L; j += 4) {
                int c = edge_col[g + j];
                float v = edge_val[g + j] * scales[c];
                uint2 qv = *(const uint2*)(supQ + (((unsigned)c) << 7) + f8x8);
                a0 = fmaf(v, (float)( qv.x        & 0xffu), a0);
                a1 = fmaf(v, (float)((qv.x >> 8)  & 0xffu), a1);
                a2 = fmaf(v, (float)((qv.x >> 16) & 0xffu), a2);
                a3 = fmaf(v, (float)( qv.x >> 24        ), a3);
                a4 = fmaf(v, (float)( qv.y        & 0xffu), a4);
                a5 = fmaf(v, (float)((qv.y >> 8)  & 0xffu), a5);
                a6 = fmaf(v, (float)((qv.y >> 16) & 0xffu), a6);
                a7 = fmaf(v, (float)( qv.y >> 24        ), a7);
                svf += v;
            }
            a0 += __shfl_xor(a0, 16); a1 += __shfl_xor(a1, 16);
            a2 += __shfl_xor(a2, 16); a3 += __shfl_xor(a3, 16);
            a4 += __shfl_xor(a4, 16); a5 += __shfl_xor(a5, 16);
            a6 += __shfl_xor(a6, 16); a7 += __shfl_xor(a7, 16);
            svf += __shfl_xor(svf, 16);
            a0 += __shfl_xor(a0, 32); a1 += __shfl_xor(a1, 32);
            a2 += __shfl_xor(a2, 32); a3 += __shfl_xor(a3, 32);
            a4 += __shfl_xor(a4, 32); a5 += __shfl_xor(a5, 32);
            a6 += __shfl_xor(a6, 32); a7 += __shfl_xor(a7, 32);
            svf += __shfl_xor(svf, 32);
            float h0 = fmaf(-128.f, svf, a0) + blo.x;
            float h1 = fmaf(-128.f, svf, a1) + blo.y;
            float h2 = fmaf(-128.f, svf, a2) + blo.z;
            float h3 = fmaf(-128.f, svf, a3) + blo.w;
            float h4 = fmaf(-128.f, svf, a4) + bhi.x;
            float h5 = fmaf(-128.f, svf, a5) + bhi.y;
            float h6 = fmaf(-128.f, svf, a6) + bhi.z;
            float h7 = fmaf(-128.f, svf, a7) + bhi.w;
            m0 = fmaxf(m0, fmaxf(h0, 0.f)); m1 = fmaxf(m1, fmaxf(h1, 0.f));
            m2 = fmaxf(m2, fmaxf(h2, 0.f)); m3 = fmaxf(m3, fmaxf(h3, 0.f));
            m4 = fmaxf(m4, fmaxf(h4, 0.f)); m5 = fmaxf(m5, fmaxf(h5, 0.f));
            m6 = fmaxf(m6, fmaxf(h6, 0.f)); m7 = fmaxf(m7, fmaxf(h7, 0.f));
        }
    }

    // --- cross-wave max exchange (all eh groups identical post-reduction) ---
    if (eh == 0) {
        xch[w][f8][0] = make_float4(m0, m1, m2, m3);
        xch[w][f8][1] = make_float4(m4, m5, m6, m7);
    }
    __syncthreads();
    float4 p0 = xch[0][f8][0], p1 = xch[0][f8][1];
    float4 q0 = xch[1][f8][0], q1 = xch[1][f8][1];
    float o0 = fmaxf(p0.x, q0.x), o1 = fmaxf(p0.y, q0.y);
    float o2 = fmaxf(p0.z, q0.z), o3 = fmaxf(p0.w, q0.w);
    float o4 = fmaxf(p1.x, q1.x), o5 = fmaxf(p1.y, q1.y);
    float o6 = fmaxf(p1.z, q1.z), o7 = fmaxf(p1.w, q1.w);

    // --- log_softmax over 128 feats (reduce across 16 f8 octets) ---
    float M = fmaxf(fmaxf(fmaxf(o0, o1), fmaxf(o2, o3)),
                    fmaxf(fmaxf(o4, o5), fmaxf(o6, o7)));
#pragma unroll
    for (int o = 8; o >= 1; o >>= 1) M = fmaxf(M, __shfl_xor(M, o));
    float S = __expf(o0 - M) + __expf(o1 - M) + __expf(o2 - M) + __expf(o3 - M)
            + __expf(o4 - M) + __expf(o5 - M) + __expf(o6 - M) + __expf(o7 - M);
#pragma unroll
    for (int o = 8; o >= 1; o >>= 1) S += __shfl_xor(S, o);

    if (w == 0 && eh == 0) {
        float ls = __logf(S);
        float* orow = out + i * 128 + f8 * 8;
        *(float4*)orow       = make_float4(o0 - M - ls, o1 - M - ls, o2 - M - ls, o3 - M - ls);
        *(float4*)(orow + 4) = make_float4(o4 - M - ls, o5 - M - ls, o6 - M - ls, o7 - M - ls);
    }
}

// ---------------------------------------------------------------------------
extern "C" void kernel_launch(void* const* d_in, const int* in_sizes, int n_in,
                              void* d_out, int out_size, void* d_ws, size_t ws_size,
                              hipStream_t stream) {
    const float* x        = (const float*)d_in[0];
    const float* W        = (const float*)d_in[1];
    const float* b        = (const float*)d_in[2];
    const float* edge_val = (const float*)d_in[3];
    const int*   edge_row = (const int*)d_in[4];
    const int*   edge_col = (const int*)d_in[5];
    float* out = (float*)d_out;

    char* ws = (char*)d_ws;
    unsigned char*  supQ    = (unsigned char*)ws;                   // 17,920,000 B
    float*          scales  = (float*)(ws + 17920000);              //    560,000 B
    int*            row_ptr = (int*)(ws + 18480000);                //    560,004 B

    gemm_prep_kernel<<<GEMM_BLOCKS + PREP_BLOCKS, 256, 0, stream>>>(
        x, W, supQ, scales, edge_row, row_ptr);
    agg_kernel<<<NODES_PER_FRAME, 128, 0, stream>>>(supQ, scales, b, edge_val, edge_col,
                                                    row_ptr, out);
}

// Round 10
// 205.928 us; speedup vs baseline: 1.0979x; 1.0979x over previous
//
#include <hip/hip_runtime.h>
#include <hip/hip_bf16.h>

#define N_NODES 140000
#define N_EDGES 2240000
#define NFEAT 128
#define NHID 128
#define N_FRAMES 14
#define NODES_PER_FRAME 10000
#define CAP 352            // int2 LDS slots per wave (7 frames padded to x8)

typedef __attribute__((ext_vector_type(8))) short frag_b16;
typedef __attribute__((ext_vector_type(4))) int frag_i4;
typedef __attribute__((ext_vector_type(4))) float f32x4;

__device__ __forceinline__ unsigned short f2bf(float f) {
    union { float f; unsigned int u; } v; v.f = f;
    unsigned int r = v.u + 0x7fffu + ((v.u >> 16) & 1u);   // RNE
    return (unsigned short)(r >> 16);
}
__device__ __forceinline__ int pk_bf16(float a, float b) {
    union { __hip_bfloat162 h; int i; } u;
    u.h = __float22bfloat162_rn(make_float2(a, b));        // v_cvt_pk_bf16_f32
    return u.i;
}

// ---------------------------------------------------------------------------
// Prep (merged, runs first): W^T bf16 conversion + CSR row offsets.
// ---------------------------------------------------------------------------
__global__ void prep_kernel(const float* __restrict__ W, unsigned short* __restrict__ WT,
                            const int* __restrict__ edge_row, int* __restrict__ row_ptr) {
    int e = blockIdx.x * blockDim.x + threadIdx.x;
    if (e < NFEAT * NHID) {
        int k = e >> 7, n = e & 127;
        WT[n * 128 + k] = f2bf(W[e]);
    }
    if (e < N_EDGES) {
        int r = edge_row[e];
        int prev = (e == 0) ? -1 : edge_row[e - 1];
        for (int q = prev + 1; q <= r; ++q) row_ptr[q] = e;
        if (e == N_EDGES - 1) {
            for (int q = r + 1; q <= N_NODES; ++q) row_ptr[q] = N_EDGES;
        }
    }
}

// ---------------------------------------------------------------------------
// GEMM: support = x @ W via mfma_f32_16x16x32_bf16 (operands swapped so each
// lane's 4 acc regs = 4 consecutive features of one node). Epilogue:
// quantize each node row to biased u8 with per-row scale:
//   u = rint(S * 127/rowmax) + 128,  scales[node] = rowmax/127
// Row = 128 B -> ONE L2 line per downstream gather.
// ---------------------------------------------------------------------------
#define WT_STRIDE 136

__global__ __launch_bounds__(256) void gemm_kernel(
        const float* __restrict__ x, const unsigned short* __restrict__ WT,
        unsigned char* __restrict__ supQ, float* __restrict__ scales) {
    __shared__ unsigned short wt_lds[128 * WT_STRIDE];

    const uint4* WTv = (const uint4*)WT;               // 2048 uint4
    for (int idx = threadIdx.x; idx < 2048; idx += 256) {
        uint4 d = WTv[idx];
        int elem = idx << 3;
        int n = elem >> 7, k = elem & 127;
        *(uint4*)&wt_lds[n * WT_STRIDE + k] = d;
    }

    int wave = threadIdx.x >> 6;
    int lane = threadIdx.x & 63;
    int m = lane & 15;
    int q = lane >> 4;

    long row0 = (long)blockIdx.x * 64 + wave * 16;

    int arow = (int)row0 + m;
    if (arow >= N_NODES) arow = N_NODES - 1;
    const float* xrow = x + (long)arow * 128 + q * 8;
    frag_b16 xa[4];
#pragma unroll
    for (int ks = 0; ks < 4; ++ks) {
        float4 lo = *(const float4*)(xrow + ks * 32);
        float4 hi = *(const float4*)(xrow + ks * 32 + 4);
        union { frag_b16 f; frag_i4 i; } u;
        u.i[0] = pk_bf16(lo.x, lo.y);
        u.i[1] = pk_bf16(lo.z, lo.w);
        u.i[2] = pk_bf16(hi.x, hi.y);
        u.i[3] = pk_bf16(hi.z, hi.w);
        xa[ks] = u.f;
    }

    __syncthreads();

    if (row0 < N_NODES) {
        f32x4 acc[8];
#pragma unroll
        for (int t = 0; t < 8; ++t) acc[t] = (f32x4){0.f, 0.f, 0.f, 0.f};

#pragma unroll
        for (int t = 0; t < 8; ++t) {
            const unsigned short* bp = &wt_lds[(t * 16 + m) * WT_STRIDE + q * 8];
#pragma unroll
            for (int ks = 0; ks < 4; ++ks) {
                frag_b16 wfrag = *(const frag_b16*)(bp + ks * 32);
                acc[t] = __builtin_amdgcn_mfma_f32_16x16x32_bf16(wfrag, xa[ks], acc[t], 0, 0, 0);
            }
        }

        // --- int8 row quantization epilogue ---
        float amax = 0.f;
#pragma unroll
        for (int t = 0; t < 8; ++t)
#pragma unroll
            for (int r = 0; r < 4; ++r) amax = fmaxf(amax, fabsf(acc[t][r]));
        amax = fmaxf(amax, __shfl_xor(amax, 16));
        amax = fmaxf(amax, __shfl_xor(amax, 32));
        float rinv = amax > 0.f ? 127.f / amax : 0.f;

        long node = row0 + m;
        if (node < N_NODES) {
            if (q == 0) scales[node] = amax * (1.f / 127.f);
            unsigned char* srow = supQ + node * 128;
#pragma unroll
            for (int t = 0; t < 8; ++t) {
                unsigned u0 = (unsigned)(rintf(acc[t][0] * rinv) + 128.f);
                unsigned u1 = (unsigned)(rintf(acc[t][1] * rinv) + 128.f);
                unsigned u2 = (unsigned)(rintf(acc[t][2] * rinv) + 128.f);
                unsigned u3 = (unsigned)(rintf(acc[t][3] * rinv) + 128.f);
                *(unsigned*)(srow + t * 16 + q * 4) = u0 | (u1 << 8) | (u2 << 16) | (u3 << 24);
            }
        }
    }
}

// ---------------------------------------------------------------------------
// Fused aggregation v7 = R7's PLAIN inner loop (best measured: 63 µs) +
// in-staging scale fold (best measured placement). NO pipeline (R8 lost),
// NO staging shuffles (R9 lost).
// Block = 128 thr = 2 waves = 1 output node. Wave w: frames [7w, 7w+6].
// Lane = (eh = lane>>4: edge-of-quad, f8 = lane&15: feature octet) -> one
// dwordx2 gather = 8 features, 4 edges per wave-instruction, one 128B line
// per edge row. eBuf stores {col<<7, valp = edge_val*scales[col]}.
// -128 bias folded as one fma with svf = per-frame sum of valp (accumulated
// in-loop). Segments padded-to-8 with {0,0} (exact fma identity, row-0 pads
// cache-hot). Wave-uniform global fallback if padded total > CAP.
// ---------------------------------------------------------------------------
__global__ __launch_bounds__(128) void agg_kernel(
        const unsigned char* __restrict__ supQ, const float* __restrict__ scales,
        const float* __restrict__ b,
        const float* __restrict__ edge_val, const int* __restrict__ edge_col,
        const int* __restrict__ row_ptr, float* __restrict__ out) {
    __shared__ int    segStart[2][8];
    __shared__ int    segLen[2][8];
    __shared__ int    segOff[2][8];
    __shared__ int2   eBuf[2][CAP];
    __shared__ float4 xch[2][16][2];

    const int i = blockIdx.x;
    const int lane = threadIdx.x & 63;
    const int w = threadIdx.x >> 6;
    const int eh = lane >> 4;                          // edge-of-quad 0..3
    const int f8 = lane & 15;                          // feature octet
    const unsigned f8x8 = (unsigned)f8 * 8u;

    // --- CSR ranges in lanes 0..6; padded-to-8 exclusive scan ---
    int a = 0, len = 0;
    if (lane < 7) {
        int n = (w * 7 + lane) * NODES_PER_FRAME + i;
        a = row_ptr[n];
        len = row_ptr[n + 1] - a;
    }
    int len8 = (len + 7) & ~7;
    int off = 0;
#pragma unroll
    for (int f2 = 0; f2 < 7; ++f2) {
        int L2 = __shfl(len8, f2);
        if (f2 < lane) off += L2;
    }
    if (lane < 7) { segStart[w][lane] = a; segLen[w][lane] = len; segOff[w][lane] = off; }
    if (lane == 6) segOff[w][7] = off + len8;
    __syncthreads();

    const bool fit = segOff[w][7] <= CAP;              // wave-uniform

    // --- stage (col<<7, valp) into LDS, zero-padded per frame ---
    if (fit) {
#pragma unroll 1
        for (int f = 0; f < 7; ++f) {
            int g = segStart[w][f], s = segOff[w][f], L = segLen[w][f];
            int L8 = (L + 7) & ~7;
            for (int j = lane; j < L8; j += 64) {
                int2 v = make_int2(0, 0);
                if (j < L) {
                    int c = edge_col[g + j];
                    v.x = c << 7;
                    v.y = __float_as_int(edge_val[g + j] * scales[c]);
                }
                eBuf[w][s + j] = v;
            }
        }
    }
    __syncthreads();

    const float4 blo = *(const float4*)&b[f8 * 8];
    const float4 bhi = *(const float4*)&b[f8 * 8 + 4];
    float m0 = 0.f, m1 = 0.f, m2 = 0.f, m3 = 0.f;      // relu => max >= 0
    float m4 = 0.f, m5 = 0.f, m6 = 0.f, m7 = 0.f;

    if (fit) {
#pragma unroll 1
        for (int f = 0; f < 7; ++f) {
            int s = segOff[w][f];
            int e8 = s + ((segLen[w][f] + 7) & ~7);
            float a0 = 0.f, a1 = 0.f, a2 = 0.f, a3 = 0.f;
            float a4 = 0.f, a5 = 0.f, a6 = 0.f, a7 = 0.f, svf = 0.f;
            for (int j = s; j < e8; j += 8) {
                int2 e0 = eBuf[w][j + eh];
                int2 e1 = eBuf[w][j + 4 + eh];
                uint2 q0 = *(const uint2*)(supQ + ((unsigned)e0.x | f8x8));
                uint2 q1 = *(const uint2*)(supQ + ((unsigned)e1.x | f8x8));
                float v0 = __int_as_float(e0.y);
                float v1 = __int_as_float(e1.y);
                a0 = fmaf(v0, (float)( q0.x        & 0xffu), a0);
                a1 = fmaf(v0, (float)((q0.x >> 8)  & 0xffu), a1);
                a2 = fmaf(v0, (float)((q0.x >> 16) & 0xffu), a2);
                a3 = fmaf(v0, (float)( q0.x >> 24        ), a3);
                a4 = fmaf(v0, (float)( q0.y        & 0xffu), a4);
                a5 = fmaf(v0, (float)((q0.y >> 8)  & 0xffu), a5);
                a6 = fmaf(v0, (float)((q0.y >> 16) & 0xffu), a6);
                a7 = fmaf(v0, (float)( q0.y >> 24        ), a7);
                svf += v0;
                a0 = fmaf(v1, (float)( q1.x        & 0xffu), a0);
                a1 = fmaf(v1, (float)((q1.x >> 8)  & 0xffu), a1);
                a2 = fmaf(v1, (float)((q1.x >> 16) & 0xffu), a2);
                a3 = fmaf(v1, (float)( q1.x >> 24        ), a3);
                a4 = fmaf(v1, (float)( q1.y        & 0xffu), a4);
                a5 = fmaf(v1, (float)((q1.y >> 8)  & 0xffu), a5);
                a6 = fmaf(v1, (float)((q1.y >> 16) & 0xffu), a6);
                a7 = fmaf(v1, (float)( q1.y >> 24        ), a7);
                svf += v1;
            }
            // reduce across the 4 edge-quads (xor 16, 32)
            a0 += __shfl_xor(a0, 16); a1 += __shfl_xor(a1, 16);
            a2 += __shfl_xor(a2, 16); a3 += __shfl_xor(a3, 16);
            a4 += __shfl_xor(a4, 16); a5 += __shfl_xor(a5, 16);
            a6 += __shfl_xor(a6, 16); a7 += __shfl_xor(a7, 16);
            svf += __shfl_xor(svf, 16);
            a0 += __shfl_xor(a0, 32); a1 += __shfl_xor(a1, 32);
            a2 += __shfl_xor(a2, 32); a3 += __shfl_xor(a3, 32);
            a4 += __shfl_xor(a4, 32); a5 += __shfl_xor(a5, 32);
            a6 += __shfl_xor(a6, 32); a7 += __shfl_xor(a7, 32);
            svf += __shfl_xor(svf, 32);
            float h0 = fmaf(-128.f, svf, a0) + blo.x;
            float h1 = fmaf(-128.f, svf, a1) + blo.y;
            float h2 = fmaf(-128.f, svf, a2) + blo.z;
            float h3 = fmaf(-128.f, svf, a3) + blo.w;
            float h4 = fmaf(-128.f, svf, a4) + bhi.x;
            float h5 = fmaf(-128.f, svf, a5) + bhi.y;
            float h6 = fmaf(-128.f, svf, a6) + bhi.z;
            float h7 = fmaf(-128.f, svf, a7) + bhi.w;
            m0 = fmaxf(m0, fmaxf(h0, 0.f)); m1 = fmaxf(m1, fmaxf(h1, 0.f));
            m2 = fmaxf(m2, fmaxf(h2, 0.f)); m3 = fmaxf(m3, fmaxf(h3, 0.f));
            m4 = fmaxf(m4, fmaxf(h4, 0.f)); m5 = fmaxf(m5, fmaxf(h5, 0.f));
            m6 = fmaxf(m6, fmaxf(h6, 0.f)); m7 = fmaxf(m7, fmaxf(h7, 0.f));
        }
    } else {
        // safety fallback: direct global reads, same math, quads split by eh
#pragma unroll 1
        for (int f = 0; f < 7; ++f) {
            int g = segStart[w][f], L = segLen[w][f];
            float a0 = 0.f, a1 = 0.f, a2 = 0.f, a3 = 0.f;
            float a4 = 0.f, a5 = 0.f, a6 = 0.f, a7 = 0.f, svf = 0.f;
            for (int j = eh; j < L; j += 4) {
                int c = edge_col[g + j];
                float v = edge_val[g + j] * scales[c];
                uint2 qv = *(const uint2*)(supQ + (((unsigned)c) << 7) + f8x8);
                a0 = fmaf(v, (float)( qv.x        & 0xffu), a0);
                a1 = fmaf(v, (float)((qv.x >> 8)  & 0xffu), a1);
                a2 = fmaf(v, (float)((qv.x >> 16) & 0xffu), a2);
                a3 = fmaf(v, (float)( qv.x >> 24        ), a3);
                a4 = fmaf(v, (float)( qv.y        & 0xffu), a4);
                a5 = fmaf(v, (float)((qv.y >> 8)  & 0xffu), a5);
                a6 = fmaf(v, (float)((qv.y >> 16) & 0xffu), a6);
                a7 = fmaf(v, (float)( qv.y >> 24        ), a7);
                svf += v;
            }
            a0 += __shfl_xor(a0, 16); a1 += __shfl_xor(a1, 16);
            a2 += __shfl_xor(a2, 16); a3 += __shfl_xor(a3, 16);
            a4 += __shfl_xor(a4, 16); a5 += __shfl_xor(a5, 16);
            a6 += __shfl_xor(a6, 16); a7 += __shfl_xor(a7, 16);
            svf += __shfl_xor(svf, 16);
            a0 += __shfl_xor(a0, 32); a1 += __shfl_xor(a1, 32);
            a2 += __shfl_xor(a2, 32); a3 += __shfl_xor(a3, 32);
            a4 += __shfl_xor(a4, 32); a5 += __shfl_xor(a5, 32);
            a6 += __shfl_xor(a6, 32); a7 += __shfl_xor(a7, 32);
            svf += __shfl_xor(svf, 32);
            float h0 = fmaf(-128.f, svf, a0) + blo.x;
            float h1 = fmaf(-128.f, svf, a1) + blo.y;
            float h2 = fmaf(-128.f, svf, a2) + blo.z;
            float h3 = fmaf(-128.f, svf, a3) + blo.w;
            float h4 = fmaf(-128.f, svf, a4) + bhi.x;
            float h5 = fmaf(-128.f, svf, a5) + bhi.y;
            float h6 = fmaf(-128.f, svf, a6) + bhi.z;
            float h7 = fmaf(-128.f, svf, a7) + bhi.w;
            m0 = fmaxf(m0, fmaxf(h0, 0.f)); m1 = fmaxf(m1, fmaxf(h1, 0.f));
            m2 = fmaxf(m2, fmaxf(h2, 0.f)); m3 = fmaxf(m3, fmaxf(h3, 0.f));
            m4 = fmaxf(m4, fmaxf(h4, 0.f)); m5 = fmaxf(m5, fmaxf(h5, 0.f));
            m6 = fmaxf(m6, fmaxf(h6, 0.f)); m7 = fmaxf(m7, fmaxf(h7, 0.f));
        }
    }

    // --- cross-wave max exchange (all eh groups identical post-reduction) ---
    if (eh == 0) {
        xch[w][f8][0] = make_float4(m0, m1, m2, m3);
        xch[w][f8][1] = make_float4(m4, m5, m6, m7);
    }
    __syncthreads();
    float4 p0 = xch[0][f8][0], p1 = xch[0][f8][1];
    float4 q0 = xch[1][f8][0], q1 = xch[1][f8][1];
    float o0 = fmaxf(p0.x, q0.x), o1 = fmaxf(p0.y, q0.y);
    float o2 = fmaxf(p0.z, q0.z), o3 = fmaxf(p0.w, q0.w);
    float o4 = fmaxf(p1.x, q1.x), o5 = fmaxf(p1.y, q1.y);
    float o6 = fmaxf(p1.z, q1.z), o7 = fmaxf(p1.w, q1.w);

    // --- log_softmax over 128 feats (reduce across 16 f8 octets) ---
    float M = fmaxf(fmaxf(fmaxf(o0, o1), fmaxf(o2, o3)),
                    fmaxf(fmaxf(o4, o5), fmaxf(o6, o7)));
#pragma unroll
    for (int o = 8; o >= 1; o >>= 1) M = fmaxf(M, __shfl_xor(M, o));
    float S = __expf(o0 - M) + __expf(o1 - M) + __expf(o2 - M) + __expf(o3 - M)
            + __expf(o4 - M) + __expf(o5 - M) + __expf(o6 - M) + __expf(o7 - M);
#pragma unroll
    for (int o = 8; o >= 1; o >>= 1) S += __shfl_xor(S, o);

    if (w == 0 && eh == 0) {
        float ls = __logf(S);
        float* orow = out + i * 128 + f8 * 8;
        *(float4*)orow       = make_float4(o0 - M - ls, o1 - M - ls, o2 - M - ls, o3 - M - ls);
        *(float4*)(orow + 4) = make_float4(o4 - M - ls, o5 - M - ls, o6 - M - ls, o7 - M - ls);
    }
}

// ---------------------------------------------------------------------------
extern "C" void kernel_launch(void* const* d_in, const int* in_sizes, int n_in,
                              void* d_out, int out_size, void* d_ws, size_t ws_size,
                              hipStream_t stream) {
    const float* x        = (const float*)d_in[0];
    const float* W        = (const float*)d_in[1];
    const float* b        = (const float*)d_in[2];
    const float* edge_val = (const float*)d_in[3];
    const int*   edge_row = (const int*)d_in[4];
    const int*   edge_col = (const int*)d_in[5];
    float* out = (float*)d_out;

    char* ws = (char*)d_ws;
    unsigned char*  supQ    = (unsigned char*)ws;                   // 17,920,000 B
    float*          scales  = (float*)(ws + 17920000);              //    560,000 B
    unsigned short* WT      = (unsigned short*)(ws + 18480000);     //     32,768 B
    int*            row_ptr = (int*)(ws + 18512768);                //    560,004 B

    prep_kernel<<<(N_EDGES + 255) / 256, 256, 0, stream>>>(W, WT, edge_row, row_ptr);
    gemm_kernel<<<(N_NODES + 63) / 64, 256, 0, stream>>>(x, WT, supQ, scales);
    agg_kernel<<<NODES_PER_FRAME, 128, 0, stream>>>(supQ, scales, b, edge_val, edge_col,
                                                    row_ptr, out);
}